// Round 8
// baseline (38.672 us; speedup 1.0000x reference)
//
#include <hip/hip_runtime.h>

// Problem constants (match reference: B=8, N=8192, D=256, M=2)
#define NN 8192
#define DD 256
#define NH (NN / 2)
#define BB 8
#define RPW 8             // rows per wave per tile
#define WPB 4             // waves per block
#define RPT (RPW * WPB)   // 32 rows per tile
#define TPB 2             // tiles per block (software-pipelined)
#define SROWS (RPT + 4)   // 36 staged rows per tile (halo 2 each side)
#define LPW (SROWS / WPB) // 9 staging loads per wave per tile
#define NBLK (BB * NN / (RPT * TPB))  // 1024
#define CPX (NBLK / 8)                // 128 blocks per XCD chunk (== one batch b)

__device__ __forceinline__ float4 f4_scale(float s, float4 v) {
    return make_float4(s * v.x, s * v.y, s * v.z, s * v.w);
}
__device__ __forceinline__ float4 f4_fma(float s, float4 v, float4 a) {
    return make_float4(fmaf(s, v.x, a.x), fmaf(s, v.y, a.y),
                       fmaf(s, v.z, a.z), fmaf(s, v.w, a.w));
}

__global__ __launch_bounds__(256) void dhhp_kernel(
    const float* __restrict__ x,
    const float* __restrict__ gl_ii, const float* __restrict__ gl_ij,
    const float* __restrict__ gl_ji, const float* __restrict__ gl_jj,
    const float* __restrict__ gu_ii, const float* __restrict__ gu_ij,
    const float* __restrict__ gu_ji, const float* __restrict__ gu_jj,
    const float* __restrict__ diag, const int* __restrict__ transform,
    float* __restrict__ out)
{
    __shared__ float smem[TPB * SROWS * DD];   // 72 KB: two tile buffers

    // XCD-aware swizzle: each XCD gets a contiguous 128-block chunk == one batch.
    const int bid = blockIdx.x;
    const int swz = (bid & 7) * CPX + (bid >> 3);
    const int b   = swz >> 7;            // 128 blocks per batch
    const int t0  = (swz & 127) << 6;    // block's first output row (64-row superblock)
    const int w   = __builtin_amdgcn_readfirstlane(threadIdx.x >> 6);
    const int col = (threadIdx.x & 63) << 2;   // float4 per lane
    const int tr  = *transform;

    const float* xb  = x    + (size_t)b * NN * DD;
    const float* db  = diag + (size_t)b * NN;
    const float* uii = gu_ii + (size_t)b * (NN - 1);
    const float* uij = gu_ij + (size_t)b * (NN - 1);
    const float* uji = gu_ji + (size_t)b * (NN - 1);
    const float* ujj = gu_jj + (size_t)b * (NN - 1);
    const float* lii = gl_ii + (size_t)b * (NN - 1);
    const float* lij = gl_ij + (size_t)b * (NN - 1);
    const float* lji = gl_ji + (size_t)b * (NN - 1);
    const float* ljj = gl_jj + (size_t)b * (NN - 1);
    float* ob = out + (size_t)b * NN * DD;

    // ---- async stage of one 36-row tile into LDS buffer `buf` (9 loads/wave) ----
    auto stageTile = [&](int tb, int buf) {
        #pragma unroll
        for (int q = 0; q < LPW; ++q) {
            const int s  = w + q * WPB;                 // LDS row slot (wave-uniform)
            const int i  = tb - 2 + s;                  // xP row index
            const int ic = i < 0 ? 0 : (i > NN - 1 ? NN - 1 : i);
            const int r  = tr ? ((ic < NH) ? (ic << 1) : (((ic - NH) << 1) | 1)) : ic;
            const float* gp = xb + (size_t)r * DD + col;        // per-lane global src
            float*       lp = smem + (size_t)(buf * SROWS + s) * DD;  // uniform LDS base
            __builtin_amdgcn_global_load_lds(
                (const __attribute__((address_space(1))) void*)gp,
                (__attribute__((address_space(3))) void*)lp, 16, 0, 0);
        }
    };

    // ---- compute + store this wave's 8 rows of one tile from LDS ----
    auto computeTile = [&](int tb, int buf) {
        const int j0 = tb + (w << 3);
        const float* sb = smem + (size_t)buf * SROWS * DD;

        auto xRow = [&](int i) -> float4 {              // i may be ghost (<0 / >N-1)
            const int s = i - (tb - 2);
            float4 v = *reinterpret_cast<const float4*>(sb + (size_t)s * DD + col);
            if (!tr) {
                const int ic = i < 0 ? 0 : (i > NN - 1 ? NN - 1 : i);
                v = f4_scale(db[ic], v);
            }
            return v;
        };
        auto yInner = [&](int i, float4 xm, float4 xc, float4 xp) -> float4 {
            float lo  = uji[i - 1];
            float cjj = ujj[i - 1];
            float dm  = cjj * uii[i];
            float hi  = cjj * uij[i];
            float4 r = f4_scale(lo, xm);
            r = f4_fma(dm, xc, r);
            r = f4_fma(hi, xp, r);
            return r;
        };
        auto yAny = [&](int i, float4 xm, float4 xc, float4 xp) -> float4 {
            int ic = i < 0 ? 0 : (i > NN - 1 ? NN - 1 : i);
            if (ic == 0)      return f4_fma(uii[0], xc, f4_scale(uij[0], xp));
            if (ic == NN - 1) return f4_fma(uji[NN - 2], xm, f4_scale(ujj[NN - 2], xc));
            return yInner(ic, xm, xc, xp);
        };
        auto zInner = [&](int j, float4 ym, float4 yc, float4 yp) -> float4 {
            float ci = lii[j];
            float lo = ci * lji[j - 1];
            float dm = ci * ljj[j - 1];
            float hi = lij[j];
            float4 r = f4_scale(lo, ym);
            r = f4_fma(dm, yc, r);
            r = f4_fma(hi, yp, r);
            return r;
        };
        auto zAny = [&](int j, float4 ym, float4 yc, float4 yp) -> float4 {
            if (j == 0)      return f4_fma(lii[0], yc, f4_scale(lij[0], yp));
            if (j == NN - 1) return f4_fma(lji[NN - 2], ym, f4_scale(ljj[NN - 2], yc));
            return zInner(j, ym, yc, yp);
        };
        auto storeRow = [&](int j, float4 z) {
            int jo;
            float4 o;
            if (tr) { o = f4_scale(db[j], z); jo = j; }
            else    { o = z; jo = (j & 1) ? (NH + (j >> 1)) : (j >> 1); }
            *reinterpret_cast<float4*>(ob + (size_t)jo * DD + col) = o;
        };

        float4 xr[RPW + 4];
        float4 yr[RPW + 2];
        const bool interior = (j0 >= 2) && (j0 <= NN - RPW - 2);

        if (interior) {
            #pragma unroll
            for (int t = 0; t < RPW + 4; ++t) xr[t] = xRow(j0 - 2 + t);
            #pragma unroll
            for (int t = 0; t < RPW + 2; ++t)
                yr[t] = yInner(j0 - 1 + t, xr[t], xr[t + 1], xr[t + 2]);
            #pragma unroll
            for (int t = 0; t < RPW; ++t)
                storeRow(j0 + t, zInner(j0 + t, yr[t], yr[t + 1], yr[t + 2]));
        } else {
            #pragma unroll
            for (int t = 0; t < RPW + 4; ++t) xr[t] = xRow(j0 - 2 + t);
            #pragma unroll
            for (int t = 0; t < RPW + 2; ++t)
                yr[t] = yAny(j0 - 1 + t, xr[t], xr[t + 1], xr[t + 2]);
            #pragma unroll
            for (int t = 0; t < RPW; ++t)
                storeRow(j0 + t, zAny(j0 + t, yr[t], yr[t + 1], yr[t + 2]));
        }
    };

    // ---- pipelined schedule: B's loads stay in flight across A's compute+stores ----
    stageTile(t0, 0);            // 9 loads/wave (tile A)
    stageTile(t0 + RPT, 1);      // 9 loads/wave (tile B) — 18 outstanding

    asm volatile("s_waitcnt vmcnt(9)" ::: "memory");   // A landed; B still in flight
    __builtin_amdgcn_sched_barrier(0);
    __builtin_amdgcn_s_barrier();

    computeTile(t0, 0);          // A's stores overlap B's in-flight loads

    // in-order vmem retirement: <=8 outstanding (the 8 stores) => all B loads done
    asm volatile("s_waitcnt vmcnt(8)" ::: "memory");
    __builtin_amdgcn_sched_barrier(0);
    __builtin_amdgcn_s_barrier();

    computeTile(t0 + RPT, 1);
}

extern "C" void kernel_launch(void* const* d_in, const int* in_sizes, int n_in,
                              void* d_out, int out_size, void* d_ws, size_t ws_size,
                              hipStream_t stream) {
    const float* x     = (const float*)d_in[0];
    const float* gl_ii = (const float*)d_in[1];
    const float* gl_ij = (const float*)d_in[2];
    const float* gl_ji = (const float*)d_in[3];
    const float* gl_jj = (const float*)d_in[4];
    const float* gu_ii = (const float*)d_in[5];
    const float* gu_ij = (const float*)d_in[6];
    const float* gu_ji = (const float*)d_in[7];
    const float* gu_jj = (const float*)d_in[8];
    const float* diag  = (const float*)d_in[9];
    const int* transform = (const int*)d_in[10];
    float* out = (float*)d_out;

    dim3 grid(NBLK);      // 1024 blocks, 4 waves, 2 pipelined tiles each
    dim3 block(256);
    hipLaunchKernelGGL(dhhp_kernel, grid, block, 0, stream,
                       x, gl_ii, gl_ij, gl_ji, gl_jj,
                       gu_ii, gu_ij, gu_ji, gu_jj, diag, transform, out);
}

// Round 9
// 35.689 us; speedup vs baseline: 1.0836x; 1.0836x over previous
//
#include <hip/hip_runtime.h>

// Problem constants (match reference: B=8, N=8192, D=256, M=2)
#define NN 8192
#define DD 256
#define NH (NN / 2)
#define BB 8
#define RPW 8             // rows per wave per tile
#define WPB 4             // waves per block
#define RPT (RPW * WPB)   // 32 rows per tile
#define TPB 2             // tiles per block, register-pipelined
#define NBLK (BB * NN / (RPT * TPB))  // 1024
#define CPX (NBLK / 8)                // 128 blocks per XCD chunk (== one batch b)
#define WROWS (RPW + 4)   // 12-row register window

typedef float fx4 __attribute__((ext_vector_type(4)));

// Unsinkable 16B global load (volatile asm: issue order = program order).
__device__ __forceinline__ float4 gload4(const float* p) {
    fx4 t;
    asm volatile("global_load_dwordx4 %0, %1, off" : "=v"(t) : "v"(p) : "memory");
    return make_float4(t.x, t.y, t.z, t.w);
}

__device__ __forceinline__ float4 f4_scale(float s, float4 v) {
    return make_float4(s * v.x, s * v.y, s * v.z, s * v.w);
}
__device__ __forceinline__ float4 f4_fma(float s, float4 v, float4 a) {
    return make_float4(fmaf(s, v.x, a.x), fmaf(s, v.y, a.y),
                       fmaf(s, v.z, a.z), fmaf(s, v.w, a.w));
}

__global__ __launch_bounds__(256) void dhhp_kernel(
    const float* __restrict__ x,
    const float* __restrict__ gl_ii, const float* __restrict__ gl_ij,
    const float* __restrict__ gl_ji, const float* __restrict__ gl_jj,
    const float* __restrict__ gu_ii, const float* __restrict__ gu_ij,
    const float* __restrict__ gu_ji, const float* __restrict__ gu_jj,
    const float* __restrict__ diag, const int* __restrict__ transform,
    float* __restrict__ out)
{
    // XCD-aware swizzle: each XCD gets a contiguous 128-block chunk == one batch.
    const int bid = blockIdx.x;
    const int swz = (bid & 7) * CPX + (bid >> 3);
    const int b   = __builtin_amdgcn_readfirstlane(swz >> 7);   // 128 blocks per batch
    const int t0  = __builtin_amdgcn_readfirstlane((swz & 127) << 6); // first row of 64-row superblock
    const int w   = __builtin_amdgcn_readfirstlane(threadIdx.x >> 6);
    const int col = (threadIdx.x & 63) << 2;   // float4 per lane
    const int tr  = *transform;

    const float* xb  = x    + (size_t)b * NN * DD;
    const float* db  = diag + (size_t)b * NN;
    const float* uii = gu_ii + (size_t)b * (NN - 1);
    const float* uij = gu_ij + (size_t)b * (NN - 1);
    const float* uji = gu_ji + (size_t)b * (NN - 1);
    const float* ujj = gu_jj + (size_t)b * (NN - 1);
    const float* lii = gl_ii + (size_t)b * (NN - 1);
    const float* lij = gl_ij + (size_t)b * (NN - 1);
    const float* lji = gl_ji + (size_t)b * (NN - 1);
    const float* ljj = gl_jj + (size_t)b * (NN - 1);
    float* ob = out + (size_t)b * NN * DD;

    const int j0a = t0 + (w << 3);          // tile A first output row
    const int j0b = j0a + RPT;              // tile B first output row

    // ---- window addresses for both tiles ----
    int icsA[WROWS], icsB[WROWS];
    const float* apA[WROWS];
    const float* apB[WROWS];
    #pragma unroll
    for (int t = 0; t < WROWS; ++t) {
        int ia  = j0a - 2 + t;
        int ica = ia < 0 ? 0 : (ia > NN - 1 ? NN - 1 : ia);
        icsA[t] = ica;
        int ra  = tr ? ((ica < NH) ? (ica << 1) : (((ica - NH) << 1) | 1)) : ica;
        apA[t]  = xb + (size_t)ra * DD + col;
        int ib  = j0b - 2 + t;
        int icb = ib < 0 ? 0 : (ib > NN - 1 ? NN - 1 : ib);
        icsB[t] = icb;
        int rb  = tr ? ((icb < NH) ? (icb << 1) : (((icb - NH) << 1) | 1)) : icb;
        apB[t]  = xb + (size_t)rb * DD + col;
    }

    // ---- issue ALL 24 loads back-to-back (A then B) ----
    float4 xrA[WROWS], xrB[WROWS];
    #pragma unroll
    for (int t = 0; t < WROWS; ++t) xrA[t] = gload4(apA[t]);
    #pragma unroll
    for (int t = 0; t < WROWS; ++t) xrB[t] = gload4(apB[t]);

    // ---- shared compute machinery (all coefficient indices wave-uniform -> s_load) ----
    auto yInner = [&](int i, float4 xm, float4 xc, float4 xp) -> float4 {
        float lo  = uji[i - 1];
        float cjj = ujj[i - 1];
        float dm  = cjj * uii[i];
        float hi  = cjj * uij[i];
        float4 r = f4_scale(lo, xm);
        r = f4_fma(dm, xc, r);
        r = f4_fma(hi, xp, r);
        return r;
    };
    auto yAny = [&](int i, float4 xm, float4 xc, float4 xp) -> float4 {
        int ic = i < 0 ? 0 : (i > NN - 1 ? NN - 1 : i);
        if (ic == 0)      return f4_fma(uii[0], xc, f4_scale(uij[0], xp));
        if (ic == NN - 1) return f4_fma(uji[NN - 2], xm, f4_scale(ujj[NN - 2], xc));
        return yInner(ic, xm, xc, xp);
    };
    auto zInner = [&](int j, float4 ym, float4 yc, float4 yp) -> float4 {
        float ci = lii[j];
        float lo = ci * lji[j - 1];
        float dm = ci * ljj[j - 1];
        float hi = lij[j];
        float4 r = f4_scale(lo, ym);
        r = f4_fma(dm, yc, r);
        r = f4_fma(hi, yp, r);
        return r;
    };
    auto zAny = [&](int j, float4 ym, float4 yc, float4 yp) -> float4 {
        if (j == 0)      return f4_fma(lii[0], yc, f4_scale(lij[0], yp));
        if (j == NN - 1) return f4_fma(lji[NN - 2], ym, f4_scale(ljj[NN - 2], yc));
        return zInner(j, ym, yc, yp);
    };
    auto storeRow = [&](int j, float4 z) {
        int jo;
        float4 o;
        if (tr) { o = f4_scale(db[j], z); jo = j; }
        else    { o = z; jo = (j & 1) ? (NH + (j >> 1)) : (j >> 1); }
        *reinterpret_cast<float4*>(ob + (size_t)jo * DD + col) = o;
    };
    auto computeTile = [&](int j0, float4 (&xr)[WROWS], int (&ics)[WROWS]) {
        if (!tr) {
            #pragma unroll
            for (int t = 0; t < WROWS; ++t) xr[t] = f4_scale(db[ics[t]], xr[t]);
        }
        float4 yr[RPW + 2];
        const bool interior = (j0 >= 2) && (j0 <= NN - RPW - 2);
        if (interior) {
            #pragma unroll
            for (int t = 0; t < RPW + 2; ++t)
                yr[t] = yInner(j0 - 1 + t, xr[t], xr[t + 1], xr[t + 2]);
            #pragma unroll
            for (int t = 0; t < RPW; ++t)
                storeRow(j0 + t, zInner(j0 + t, yr[t], yr[t + 1], yr[t + 2]));
        } else {
            #pragma unroll
            for (int t = 0; t < RPW + 2; ++t)
                yr[t] = yAny(j0 - 1 + t, xr[t], xr[t + 1], xr[t + 2]);
            #pragma unroll
            for (int t = 0; t < RPW; ++t)
                storeRow(j0 + t, zAny(j0 + t, yr[t], yr[t + 1], yr[t + 2]));
        }
    };

    // ---- pipelined schedule ----
    // A ready (12 B-loads still outstanding):
    asm volatile("s_waitcnt vmcnt(12)" ::: "memory");
    __builtin_amdgcn_sched_barrier(0);
    computeTile(j0a, xrA, icsA);     // A's 8 stores overlap B's in-flight loads

    // in-order vmem retirement: <=8 outstanding (the 8 stores) => all B loads done
    asm volatile("s_waitcnt vmcnt(8)" ::: "memory");
    __builtin_amdgcn_sched_barrier(0);
    computeTile(j0b, xrB, icsB);
}

extern "C" void kernel_launch(void* const* d_in, const int* in_sizes, int n_in,
                              void* d_out, int out_size, void* d_ws, size_t ws_size,
                              hipStream_t stream) {
    const float* x     = (const float*)d_in[0];
    const float* gl_ii = (const float*)d_in[1];
    const float* gl_ij = (const float*)d_in[2];
    const float* gl_ji = (const float*)d_in[3];
    const float* gl_jj = (const float*)d_in[4];
    const float* gu_ii = (const float*)d_in[5];
    const float* gu_ij = (const float*)d_in[6];
    const float* gu_ji = (const float*)d_in[7];
    const float* gu_jj = (const float*)d_in[8];
    const float* diag  = (const float*)d_in[9];
    const int* transform = (const int*)d_in[10];
    float* out = (float*)d_out;

    dim3 grid(NBLK);      // 1024 blocks, 4 waves, 2 register-pipelined tiles each
    dim3 block(256);
    hipLaunchKernelGGL(dhhp_kernel, grid, block, 0, stream,
                       x, gl_ii, gl_ij, gl_ji, gl_jj,
                       gu_ii, gu_ij, gu_ji, gu_jj, diag, transform, out);
}

// Round 10
// 27.786 us; speedup vs baseline: 1.3918x; 1.2844x over previous
//
#include <hip/hip_runtime.h>

// Problem constants (match reference: B=8, N=8192, D=256, M=2)
#define NN 8192
#define DD 256
#define NH (NN / 2)
#define BB 8
#define RPW 8    // output rows per wave
#define WPB 2    // waves per block (128-thread blocks -> 4096 blocks = 2x backfill)
#define NBLK (BB * NN / RPW / WPB)   // 4096
#define CPX (NBLK / 8)               // 512 blocks per XCD chunk (== one batch b)

__device__ __forceinline__ float4 f4_load(const float* p) {
    return *reinterpret_cast<const float4*>(p);
}
__device__ __forceinline__ float4 f4_scale(float s, float4 v) {
    return make_float4(s * v.x, s * v.y, s * v.z, s * v.w);
}
__device__ __forceinline__ float4 f4_fma(float s, float4 v, float4 a) {
    return make_float4(fmaf(s, v.x, a.x), fmaf(s, v.y, a.y),
                       fmaf(s, v.z, a.z), fmaf(s, v.w, a.w));
}

__global__ __launch_bounds__(128) void dhhp_kernel(
    const float* __restrict__ x,
    const float* __restrict__ gl_ii, const float* __restrict__ gl_ij,
    const float* __restrict__ gl_ji, const float* __restrict__ gl_jj,
    const float* __restrict__ gu_ii, const float* __restrict__ gu_ij,
    const float* __restrict__ gu_ji, const float* __restrict__ gu_jj,
    const float* __restrict__ diag, const int* __restrict__ transform,
    float* __restrict__ out)
{
    // XCD-aware swizzle: each XCD gets a contiguous 512-block chunk == one batch.
    const int bid = blockIdx.x;
    const int swz = (bid & 7) * CPX + (bid >> 3);
    int wid = swz * WPB + (threadIdx.x >> 6);
    wid = __builtin_amdgcn_readfirstlane(wid);       // wave-uniform -> SGPRs
    const int b   = wid >> 10;                       // waves per batch = NN/RPW = 1024
    const int j0  = (wid & 1023) << 3;               // * RPW
    const int col = (threadIdx.x & 63) << 2;         // float4 per lane
    const int tr  = *transform;

    const float* xb  = x    + (size_t)b * NN * DD;
    const float* db  = diag + (size_t)b * NN;
    const float* uii = gu_ii + (size_t)b * (NN - 1);
    const float* uij = gu_ij + (size_t)b * (NN - 1);
    const float* uji = gu_ji + (size_t)b * (NN - 1);
    const float* ujj = gu_jj + (size_t)b * (NN - 1);
    const float* lii = gl_ii + (size_t)b * (NN - 1);
    const float* lij = gl_ij + (size_t)b * (NN - 1);
    const float* lji = gl_ji + (size_t)b * (NN - 1);
    const float* ljj = gl_jj + (size_t)b * (NN - 1);
    float* ob = out + (size_t)b * NN * DD;

    auto permRow = [&](int i) -> int {
        return tr ? ((i < NH) ? (i << 1) : (((i - NH) << 1) | 1)) : i;
    };
    auto loadRowI = [&](int i) -> float4 {           // interior: no clamp
        float4 v = f4_load(xb + (size_t)permRow(i) * DD + col);
        if (!tr) v = f4_scale(db[i], v);
        return v;
    };
    auto loadRowC = [&](int i) -> float4 {           // edge: clamped
        int ic = i < 0 ? 0 : (i > NN - 1 ? NN - 1 : i);
        return loadRowI(ic);
    };
    auto yInner = [&](int i, float4 xm, float4 xc, float4 xp) -> float4 {
        float lo  = uji[i - 1];
        float cjj = ujj[i - 1];
        float dm  = cjj * uii[i];
        float hi  = cjj * uij[i];
        float4 r = f4_scale(lo, xm);
        r = f4_fma(dm, xc, r);
        r = f4_fma(hi, xp, r);
        return r;
    };
    // ghost rows (i<0 / i>N-1 after clamp) produce wrong-but-unused values
    auto yAny = [&](int i, float4 xm, float4 xc, float4 xp) -> float4 {
        int ic = i < 0 ? 0 : (i > NN - 1 ? NN - 1 : i);
        if (ic == 0)      return f4_fma(uii[0], xc, f4_scale(uij[0], xp));
        if (ic == NN - 1) return f4_fma(uji[NN - 2], xm, f4_scale(ujj[NN - 2], xc));
        return yInner(ic, xm, xc, xp);
    };
    auto zInner = [&](int j, float4 ym, float4 yc, float4 yp) -> float4 {
        float ci = lii[j];
        float lo = ci * lji[j - 1];
        float dm = ci * ljj[j - 1];
        float hi = lij[j];
        float4 r = f4_scale(lo, ym);
        r = f4_fma(dm, yc, r);
        r = f4_fma(hi, yp, r);
        return r;
    };
    auto zAny = [&](int j, float4 ym, float4 yc, float4 yp) -> float4 {
        if (j == 0)      return f4_fma(lii[0], yc, f4_scale(lij[0], yp));
        if (j == NN - 1) return f4_fma(lji[NN - 2], ym, f4_scale(ljj[NN - 2], yc));
        return zInner(j, ym, yc, yp);
    };
    auto storeRow = [&](int j, float4 z) {
        int jo;
        float4 o;
        if (tr) { o = f4_scale(db[j], z); jo = j; }
        else    { o = z; jo = (j & 1) ? (NH + (j >> 1)) : (j >> 1); }
        *reinterpret_cast<float4*>(ob + (size_t)jo * DD + col) = o;
    };

    const bool interior = (j0 >= 2) && (j0 <= NN - RPW - 2);

    float4 xr[RPW + 4];   // x[j0-2 .. j0+RPW+1]
    float4 yr[RPW + 2];   // y[j0-1 .. j0+RPW]

    if (interior) {
        #pragma unroll
        for (int t = 0; t < RPW + 4; ++t) xr[t] = loadRowI(j0 - 2 + t);
        #pragma unroll
        for (int t = 0; t < RPW + 2; ++t)
            yr[t] = yInner(j0 - 1 + t, xr[t], xr[t + 1], xr[t + 2]);
        #pragma unroll
        for (int t = 0; t < RPW; ++t)
            storeRow(j0 + t, zInner(j0 + t, yr[t], yr[t + 1], yr[t + 2]));
    } else {
        #pragma unroll
        for (int t = 0; t < RPW + 4; ++t) xr[t] = loadRowC(j0 - 2 + t);
        #pragma unroll
        for (int t = 0; t < RPW + 2; ++t)
            yr[t] = yAny(j0 - 1 + t, xr[t], xr[t + 1], xr[t + 2]);
        #pragma unroll
        for (int t = 0; t < RPW; ++t)
            storeRow(j0 + t, zAny(j0 + t, yr[t], yr[t + 1], yr[t + 2]));
    }
}

extern "C" void kernel_launch(void* const* d_in, const int* in_sizes, int n_in,
                              void* d_out, int out_size, void* d_ws, size_t ws_size,
                              hipStream_t stream) {
    const float* x     = (const float*)d_in[0];
    const float* gl_ii = (const float*)d_in[1];
    const float* gl_ij = (const float*)d_in[2];
    const float* gl_ji = (const float*)d_in[3];
    const float* gl_jj = (const float*)d_in[4];
    const float* gu_ii = (const float*)d_in[5];
    const float* gu_ij = (const float*)d_in[6];
    const float* gu_ji = (const float*)d_in[7];
    const float* gu_jj = (const float*)d_in[8];
    const float* diag  = (const float*)d_in[9];
    const int* transform = (const int*)d_in[10];
    float* out = (float*)d_out;

    dim3 grid(NBLK);      // 4096 blocks, 2 waves each (backfill-friendly)
    dim3 block(128);
    hipLaunchKernelGGL(dhhp_kernel, grid, block, 0, stream,
                       x, gl_ii, gl_ij, gl_ji, gl_jj,
                       gu_ii, gu_ij, gu_ji, gu_jj, diag, transform, out);
}